// Round 1
// 596.456 us; speedup vs baseline: 1.0363x; 1.0363x over previous
//
#include <hip/hip_runtime.h>
#include <math.h>

#define D_MODEL 1024
#define D_HIDDEN 4096
#define NEXP 8
#define NTOK 8192
#define CAP 1280
#define KSPLIT 4

typedef __attribute__((ext_vector_type(8))) short short8x;
typedef __attribute__((ext_vector_type(4))) short short4x;
typedef __attribute__((ext_vector_type(4))) float float4x;

__device__ __forceinline__ short f2bf(float f) {
  unsigned u = __float_as_uint(f);
  unsigned r = (u + 0x7FFFu + ((u >> 16) & 1u)) >> 16;  // RNE
  return (short)r;
}
__device__ __forceinline__ float bf2f(short s) {
  return __uint_as_float(((unsigned)(unsigned short)s) << 16);
}
// tanh-GELU via sigmoid; abs err ~5e-4, far under threshold headroom. ~8 VALU.
__device__ __forceinline__ float gelu_fast(float v) {
  float u2 = v * (1.5957691216f + 0.0713548163f * v * v);
  return v / (1.0f + __expf(-u2));
}

__device__ __forceinline__ void glds16(const void* g, void* l) {
  __builtin_amdgcn_global_load_lds(
      (const __attribute__((address_space(1))) void*)g,
      (__attribute__((address_space(3))) void*)l, 16, 0, 0);
}

// ---------------- convert x: fp32 -> bf16, same layout ----------------
__global__ __launch_bounds__(256) void convert_x_kernel(
    const float* __restrict__ x, short* __restrict__ xbf) {
  size_t i = ((size_t)blockIdx.x * 256 + threadIdx.x) * 8;
  const float4* s = (const float4*)(x + i);
  float4 a = s[0], b = s[1];
  short8x o;
  o[0] = f2bf(a.x); o[1] = f2bf(a.y); o[2] = f2bf(a.z); o[3] = f2bf(a.w);
  o[4] = f2bf(b.x); o[5] = f2bf(b.y); o[6] = f2bf(b.z); o[7] = f2bf(b.w);
  *(short8x*)(xbf + i) = o;
}

// ------- transpose+convert: in [E][K][N] fp32 -> out [E][N][K] bf16 -------
__global__ __launch_bounds__(256) void transpose_kernel(
    const float* __restrict__ in, short* __restrict__ out, int K, int N) {
  __shared__ unsigned tile[32 * 65];
  int n0 = blockIdx.x * 64, k0 = blockIdx.y * 64, e = blockIdx.z;
  int t = threadIdx.x;
  int rr = t >> 4;        // 0..15 (row within 16-row pass)
  int cc = (t & 15) * 4;  // n within tile
  const float* src = in + (size_t)e * K * N + (size_t)(k0 + rr) * N + n0 + cc;
  bool packer = (rr & 1) == 0;
  int mb = rr >> 1;
#pragma unroll
  for (int p = 0; p < 4; ++p) {
    float4 v = *(const float4*)(src + (size_t)p * 16 * N);
    float4 wv;
    wv.x = __shfl_xor(v.x, 16, 64);  // partner row r+1 (rr odd lane)
    wv.y = __shfl_xor(v.y, 16, 64);
    wv.z = __shfl_xor(v.z, 16, 64);
    wv.w = __shfl_xor(v.w, 16, 64);
    if (packer) {
      int m = p * 8 + mb;  // local kpair 0..31
      unsigned* tr = &tile[m * 65 + cc];
      tr[0] = (unsigned)(unsigned short)f2bf(v.x) |
              ((unsigned)(unsigned short)f2bf(wv.x) << 16);
      tr[1] = (unsigned)(unsigned short)f2bf(v.y) |
              ((unsigned)(unsigned short)f2bf(wv.y) << 16);
      tr[2] = (unsigned)(unsigned short)f2bf(v.z) |
              ((unsigned)(unsigned short)f2bf(wv.z) << 16);
      tr[3] = (unsigned)(unsigned short)f2bf(v.w) |
              ((unsigned)(unsigned short)f2bf(wv.w) << 16);
    }
  }
  __syncthreads();
  int n = t >> 2, q = t & 3;
  const unsigned* col = &tile[q * 8 * 65 + n];
  unsigned d[8];
#pragma unroll
  for (int j = 0; j < 8; ++j) d[j] = col[j * 65];
  short* dst = out + (size_t)e * N * K + (size_t)(n0 + n) * K + k0 + q * 16;
  ((uint4*)dst)[0] = make_uint4(d[0], d[1], d[2], d[3]);
  ((uint4*)dst)[1] = make_uint4(d[4], d[5], d[6], d[7]);
}

// ---------------- Router ----------------
__global__ __launch_bounds__(256) void router_kernel(
    const float* __restrict__ x, const float* __restrict__ rw,
    const float* __restrict__ rb, int2* __restrict__ tok_experts,
    float2* __restrict__ tok_gates) {
  int t = blockIdx.x * 4 + (threadIdx.x >> 6);
  int lane = threadIdx.x & 63;
  const float* xr = x + (size_t)t * D_MODEL;
  float acc[8];
#pragma unroll
  for (int e = 0; e < 8; ++e) acc[e] = 0.f;
#pragma unroll
  for (int kk = 0; kk < 16; ++kk) {
    int k = kk * 64 + lane;
    float xv = xr[k];
    const float4* wr = (const float4*)(rw + (size_t)k * 8);
    float4 w0 = wr[0], w1v = wr[1];
    acc[0] += xv * w0.x;  acc[1] += xv * w0.y;
    acc[2] += xv * w0.z;  acc[3] += xv * w0.w;
    acc[4] += xv * w1v.x; acc[5] += xv * w1v.y;
    acc[6] += xv * w1v.z; acc[7] += xv * w1v.w;
  }
#pragma unroll
  for (int off = 32; off > 0; off >>= 1) {
#pragma unroll
    for (int e = 0; e < 8; ++e) acc[e] += __shfl_xor(acc[e], off, 64);
  }
  if (lane == 0) {
    float lg[8];
#pragma unroll
    for (int e = 0; e < 8; ++e) lg[e] = acc[e] + rb[e];
    int e0 = 0;
#pragma unroll
    for (int e = 1; e < 8; ++e) if (lg[e] > lg[e0]) e0 = e;
    int e1 = (e0 == 0) ? 1 : 0;
#pragma unroll
    for (int e = 0; e < 8; ++e) if (e != e0 && lg[e] > lg[e1]) e1 = e;
    float mx = lg[e0];
    float s = 0.f;
#pragma unroll
    for (int e = 0; e < 8; ++e) s += expf(lg[e] - mx);
    float inv = 1.f / s;
    tok_experts[t] = make_int2(e0, e1);
    tok_gates[t] = make_float2(expf(lg[e0] - mx) * inv, expf(lg[e1] - mx) * inv);
  }
}

// ---------------- Scan ----------------
__global__ __launch_bounds__(1024) void scan_kernel(
    const int2* __restrict__ tok_experts, int* __restrict__ slot_token,
    int* __restrict__ token_rows) {
  int e = blockIdx.x;
  int tid = threadIdx.x;
  for (int i = tid; i < CAP; i += 1024) slot_token[e * CAP + i] = -1;
  __shared__ int wsum[16];
  __shared__ int running;
  if (tid == 0) running = 0;
  __syncthreads();
  int lane = tid & 63, wid = tid >> 6;
  unsigned long long lmask = (1ull << lane) - 1ull;
  for (int base = 0; base < NTOK; base += 1024) {
    int t = base + tid;
    int2 ee = tok_experts[t];
    int m = (ee.x == e || ee.y == e) ? 1 : 0;
    unsigned long long bal = __ballot(m);
    int prefix = __popcll(bal & lmask);
    if (lane == 0) wsum[wid] = (int)__popcll(bal);
    __syncthreads();
    if (tid == 0) {
      int s = running;
#pragma unroll
      for (int w = 0; w < 16; ++w) { int v = wsum[w]; wsum[w] = s; s += v; }
      running = s;
    }
    __syncthreads();
    if (m) {
      int pos = wsum[wid] + prefix;
      int which = (ee.x == e) ? 0 : 1;
      if (pos < CAP) {
        slot_token[e * CAP + pos] = t;
        token_rows[2 * t + which] = e * CAP + pos;
      } else {
        token_rows[2 * t + which] = -1;
      }
    }
    __syncthreads();
  }
}

// ================= 256x256 8-wave 4-phase pipelined GEMM =================
// MODE 1: h = gelu(gather(xbf) @ w1t[e]^T + b1[e]); grid 640 = 8e*5rt*16ct
// MODE 2: partial[ks] = h @ w2t[e][:, ks]^T (+b2 if ks==0); grid 640 = 8e*5rt*4ct*4ks
// LDS: [buf(2)][mat(2:A,B)][256 rows][64 K bf16] = 128 KiB, XOR swizzle
// chunk ^= row&7 (pre-swizzled global source; linear global_load_lds dest).
// Per K-tile (BK=64): 4 phases; each: ds_read subtile | stage 1 half-tile |
// barrier | lgkmcnt(0) | setprio(1) 16xMFMA setprio(0) | barrier.
// Counted vmcnt(4) once per K-tile (2 half-tiles in flight across barriers).

#define BARX() __builtin_amdgcn_s_barrier()
#define LGKM0()                                      \
  asm volatile("s_waitcnt lgkmcnt(0)" ::: "memory"); \
  __builtin_amdgcn_sched_barrier(0)
#define VMW(n) asm volatile("s_waitcnt vmcnt(" #n ")" ::: "memory")

template <int MODE>
__global__ __launch_bounds__(512, 2) void gemm_8phase(
    const short* __restrict__ A, const short* __restrict__ Bw,
    const float* __restrict__ bias, const int* __restrict__ slot_token,
    short* __restrict__ o0, short* __restrict__ o1, short* __restrict__ o2,
    short* __restrict__ o3) {
  constexpr int NCOL = (MODE == 1) ? D_HIDDEN : D_MODEL;   // output cols
  constexpr int ARSH = (MODE == 1) ? D_MODEL : D_HIDDEN;   // A row elems
  constexpr int BRSH = (MODE == 1) ? D_MODEL : D_HIDDEN;   // B row elems
  constexpr int NT = 16;                                   // K-tiles (K=1024)

  __shared__ __align__(1024) char lds[131072];

  int bx = blockIdx.x;
  int e = bx & 7;           // XCD pin
  int rest = bx >> 3;       // 0..79
  int rt = rest % 5;        // rt fastest: concurrent blocks share B panel
  int c2 = rest / 5;        // 0..15
  int ct, ks;
  if constexpr (MODE == 1) { ct = c2; ks = 0; }
  else { ct = c2 & 3; ks = c2 >> 2; }

  int tid = threadIdx.x;
  int w = tid >> 6, l = tid & 63;
  int wr = w >> 2, wc = w & 3;  // wave grid 2M x 4N; wave out = 128x64

  // staging: half-tile h (128 rows), instr i (64 rows): row = h*128+i*64+w*8+(l>>3)
  // source chunk pre-swizzled: c_g = (l&7) ^ (row&7) = (l&7) ^ ((l>>3)&7)
  int cg16 = (((l & 7) ^ ((l >> 3) & 7)) << 4);
  size_t koff = (size_t)ks * (D_HIDDEN / KSPLIT) * 2;  // bytes within row

  const char* ast[4];
  const char* bst[4];
#pragma unroll
  for (int h = 0; h < 2; ++h) {
#pragma unroll
    for (int i = 0; i < 2; ++i) {
      int r = h * 128 + i * 64 + w * 8 + (l >> 3);
      int p = h * 2 + i;
      if constexpr (MODE == 1) {
        int t = slot_token[e * CAP + rt * 256 + r];
        if (t < 0) t = 0;  // dropped slot: garbage row, never combined
        ast[p] = (const char*)A + (size_t)t * (ARSH * 2) + cg16;
      } else {
        ast[p] = (const char*)A + (size_t)(e * CAP + rt * 256 + r) * (ARSH * 2) +
                 koff + cg16;
      }
      bst[p] = (const char*)Bw + (size_t)(e * NCOL + ct * 256 + r) * (BRSH * 2) +
               koff + cg16;
    }
  }
  char* ldsb = (char*)lds;
  int wofs = w * 1024;

#define STG_(stg, matoff, h, ktB, buf)                                         \
  glds16(stg[(h) * 2 + 0] + (ktB),                                             \
         ldsb + (buf) * 65536 + (matoff) + (h) * 16384 + wofs);                \
  glds16(stg[(h) * 2 + 1] + (ktB),                                             \
         ldsb + (buf) * 65536 + (matoff) + (h) * 16384 + 8192 + wofs)
#define STG_A(h, ktB, buf) STG_(ast, 0, h, ktB, buf)
#define STG_B(h, ktB, buf) STG_(bst, 32768, h, ktB, buf)

  int lane_row = (l & 15) * 128;
  int ck0 = ((((l >> 4) + 0) ^ (l & 7)) << 4);  // ks=0 chunk (swizzled)
  int ck1 = ((((l >> 4) + 4) ^ (l & 7)) << 4);  // ks=1 chunk (swizzled)

  short8x av[4][2], bv[2][2];
  float4x acc[8][4];
#pragma unroll
  for (int m = 0; m < 8; ++m)
#pragma unroll
    for (int n = 0; n < 4; ++n) acc[m][n] = (float4x){0.f, 0.f, 0.f, 0.f};

#define LDA_(Mq, cur)                                                          \
  {                                                                            \
    const char* ap_ =                                                          \
        ldsb + (cur) * 65536 + wr * 16384 + (Mq) * 8192 + lane_row;            \
    av[0][0] = *(const short8x*)(ap_ + 0 * 2048 + ck0);                        \
    av[0][1] = *(const short8x*)(ap_ + 0 * 2048 + ck1);                        \
    av[1][0] = *(const short8x*)(ap_ + 1 * 2048 + ck0);                        \
    av[1][1] = *(const short8x*)(ap_ + 1 * 2048 + ck1);                        \
    av[2][0] = *(const short8x*)(ap_ + 2 * 2048 + ck0);                        \
    av[2][1] = *(const short8x*)(ap_ + 2 * 2048 + ck1);                        \
    av[3][0] = *(const short8x*)(ap_ + 3 * 2048 + ck0);                        \
    av[3][1] = *(const short8x*)(ap_ + 3 * 2048 + ck1);                        \
  }
#define LDB_(Nq, cur)                                                          \
  {                                                                            \
    const char* bp_ = ldsb + (cur) * 65536 + 32768 + wc * 8192 +               \
                      (Nq) * 4096 + lane_row;                                  \
    bv[0][0] = *(const short8x*)(bp_ + 0 * 2048 + ck0);                        \
    bv[0][1] = *(const short8x*)(bp_ + 0 * 2048 + ck1);                        \
    bv[1][0] = *(const short8x*)(bp_ + 1 * 2048 + ck0);                        \
    bv[1][1] = *(const short8x*)(bp_ + 1 * 2048 + ck1);                        \
  }
#define MFMA16(Mq, Nq)                                                         \
  __builtin_amdgcn_s_setprio(1);                                               \
  _Pragma("unroll") for (int mm = 0; mm < 4; ++mm) {                           \
    _Pragma("unroll") for (int nn = 0; nn < 2; ++nn) {                         \
      float4x* ac = &acc[(Mq) * 4 + mm][(Nq) * 2 + nn];                        \
      *ac = __builtin_amdgcn_mfma_f32_16x16x32_bf16(av[mm][0], bv[nn][0], *ac, \
                                                    0, 0, 0);                  \
      *ac = __builtin_amdgcn_mfma_f32_16x16x32_bf16(av[mm][1], bv[nn][1], *ac, \
                                                    0, 0, 0);                  \
    }                                                                          \
  }                                                                            \
  __builtin_amdgcn_s_setprio(0)

  // Prologue: K-tile0 -> buf0 (A0,B0,A1,B1), K-tile1 A0,B0 -> buf1.
  // vmcnt(4) retires all of K-tile0, leaves A0(1),B0(1) in flight (invariant).
  STG_A(0, 0, 0);
  STG_B(0, 0, 0);
  STG_A(1, 0, 0);
  STG_B(1, 0, 0);
  STG_A(0, 128, 1);
  STG_B(0, 128, 1);
  VMW(4);
  BARX();

  // Region safety (within cur buf): A0 last ds_read at ph1, restaged ph3;
  // B0 last read ph3, restaged ph4. A1/B1 of nxt buf last read in previous
  // block. Each staged half-tile is vmcnt-confirmed at the block-end wait
  // preceding its consuming block.
#define KBODY(uu, cur, nxt)                                                    \
  {                                                                            \
    int kb1 = ((uu) + 1) * 128, kb2 = ((uu) + 2) * 128;                        \
    /* ph1 */                                                                  \
    LDA_(0, cur); LDB_(0, cur);                                                \
    if ((uu) + 1 < NT) { STG_A(1, kb1, nxt); }                                 \
    BARX(); LGKM0(); MFMA16(0, 0); BARX();                                     \
    /* ph2 */                                                                  \
    LDB_(1, cur);                                                              \
    if ((uu) + 1 < NT) { STG_B(1, kb1, nxt); }                                 \
    BARX(); LGKM0(); MFMA16(0, 1); BARX();                                     \
    /* ph3 */                                                                  \
    LDA_(1, cur); LDB_(0, cur);                                                \
    if ((uu) + 2 < NT) { STG_A(0, kb2, cur); }                                 \
    BARX(); LGKM0(); MFMA16(1, 0); BARX();                                     \
    /* ph4 */                                                                  \
    LDB_(1, cur);                                                              \
    if ((uu) + 2 < NT) { STG_B(0, kb2, cur); }                                 \
    if ((uu) < NT - 2) { VMW(4); } else { VMW(0); }                            \
    BARX(); LGKM0(); MFMA16(1, 1); BARX();                                     \
  }

#pragma unroll 1
  for (int u = 0; u < NT; u += 2) {
    KBODY(u, 0, 1);
    KBODY(u + 1, 1, 0);
  }

  // ---------------- epilogue ----------------
  int q4 = (l >> 4) * 4, l15 = l & 15;
  if constexpr (MODE == 1) {
#pragma unroll
    for (int m = 0; m < 8; ++m) {
      int grow = rt * 256 + wr * 128 + m * 16 + q4;
      size_t rowb = (size_t)(e * CAP + grow) * NCOL;
#pragma unroll
      for (int n = 0; n < 4; ++n) {
        int col = ct * 256 + wc * 64 + n * 16 + l15;
        float bs = bias[e * NCOL + col];
#pragma unroll
        for (int r = 0; r < 4; ++r) {
          float v = gelu_fast(acc[m][n][r] + bs);
          o0[rowb + (size_t)r * NCOL + col] = f2bf(v);
        }
      }
    }
  } else {
    short* dst = (ks == 0) ? o0 : (ks == 1) ? o1 : (ks == 2) ? o2 : o3;
#pragma unroll
    for (int m = 0; m < 8; ++m) {
      int grow = rt * 256 + wr * 128 + m * 16 + q4;
      size_t rowb = (size_t)(e * CAP + grow) * NCOL;
#pragma unroll
      for (int n = 0; n < 4; ++n) {
        int col = ct * 256 + wc * 64 + n * 16 + l15;
        float bs = (ks == 0) ? bias[e * NCOL + col] : 0.f;
#pragma unroll
        for (int r = 0; r < 4; ++r)
          dst[rowb + (size_t)r * NCOL + col] = f2bf(acc[m][n][r] + bs);
      }
    }
  }
}

// ---------------- Combine: y[t] = sum_i g_i * sum_ks p_ks[r_i] ----------------
__global__ __launch_bounds__(256) void combine_kernel(
    const int* __restrict__ token_rows, const float2* __restrict__ tok_gates,
    const short* __restrict__ p0, const short* __restrict__ p1,
    const short* __restrict__ p2, const short* __restrict__ p3,
    float* __restrict__ y) {
  int t = blockIdx.x;
  int r0 = token_rows[2 * t], r1 = token_rows[2 * t + 1];
  float2 g = tok_gates[t];
  int d = threadIdx.x * 4;
  float4 v; v.x = v.y = v.z = v.w = 0.f;
  if (r0 >= 0) {
    size_t b = (size_t)r0 * D_MODEL + d;
    short4x a0 = *(const short4x*)(p0 + b);
    short4x a1 = *(const short4x*)(p1 + b);
    short4x a2 = *(const short4x*)(p2 + b);
    short4x a3 = *(const short4x*)(p3 + b);
    v.x += g.x * (bf2f(a0[0]) + bf2f(a1[0]) + bf2f(a2[0]) + bf2f(a3[0]));
    v.y += g.x * (bf2f(a0[1]) + bf2f(a1[1]) + bf2f(a2[1]) + bf2f(a3[1]));
    v.z += g.x * (bf2f(a0[2]) + bf2f(a1[2]) + bf2f(a2[2]) + bf2f(a3[2]));
    v.w += g.x * (bf2f(a0[3]) + bf2f(a1[3]) + bf2f(a2[3]) + bf2f(a3[3]));
  }
  if (r1 >= 0) {
    size_t b = (size_t)r1 * D_MODEL + d;
    short4x a0 = *(const short4x*)(p0 + b);
    short4x a1 = *(const short4x*)(p1 + b);
    short4x a2 = *(const short4x*)(p2 + b);
    short4x a3 = *(const short4x*)(p3 + b);
    v.x += g.y * (bf2f(a0[0]) + bf2f(a1[0]) + bf2f(a2[0]) + bf2f(a3[0]));
    v.y += g.y * (bf2f(a0[1]) + bf2f(a1[1]) + bf2f(a2[1]) + bf2f(a3[1]));
    v.z += g.y * (bf2f(a0[2]) + bf2f(a1[2]) + bf2f(a2[2]) + bf2f(a3[2]));
    v.w += g.y * (bf2f(a0[3]) + bf2f(a1[3]) + bf2f(a2[3]) + bf2f(a3[3]));
  }
  *(float4*)(y + (size_t)t * D_MODEL + d) = v;
}

extern "C" void kernel_launch(void* const* d_in, const int* in_sizes, int n_in,
                              void* d_out, int out_size, void* d_ws, size_t ws_size,
                              hipStream_t stream) {
  const float* x  = (const float*)d_in[0];
  const float* rw = (const float*)d_in[1];
  const float* rb = (const float*)d_in[2];
  const float* w1 = (const float*)d_in[3];
  const float* b1 = (const float*)d_in[4];
  const float* w2 = (const float*)d_in[5];
  const float* b2 = (const float*)d_in[6];
  float* y = (float*)d_out;
  (void)in_sizes; (void)n_in; (void)out_size; (void)ws_size;

  char* p = (char*)d_ws;
  size_t off = 0;
  auto take = [&](size_t bytes) -> void* {
    void* r = p + off;
    off = (off + bytes + 255) & ~(size_t)255;
    return r;
  };
  // identical carve to previous rounds (proven to fit ws_size)
  int2*   tok_experts = (int2*)  take((size_t)NTOK * sizeof(int2));
  float2* tok_gates   = (float2*)take((size_t)NTOK * sizeof(float2));
  int*    slot_token  = (int*)   take((size_t)NEXP * CAP * sizeof(int));
  int*    token_rows  = (int*)   take((size_t)NTOK * 2 * sizeof(int));
  short*  xbf         = (short*) take((size_t)NTOK * D_MODEL * sizeof(short));
  short*  w1t         = (short*) take((size_t)NEXP * D_HIDDEN * D_MODEL * sizeof(short));
  short*  w2t         = (short*) take((size_t)NEXP * D_MODEL * D_HIDDEN * sizeof(short));
  short*  h           = (short*) take((size_t)NEXP * CAP * D_HIDDEN * sizeof(short));
  short*  out2        = (short*) take((size_t)NEXP * CAP * D_MODEL * sizeof(short));
  // K-split partials 1..3 overlay w1t (dead after gemm1; 3x21 MB <= 67 MB)
  short* part0 = out2;
  short* part1 = w1t;
  short* part2 = w1t + (size_t)NEXP * CAP * D_MODEL;
  short* part3 = w1t + (size_t)2 * NEXP * CAP * D_MODEL;

  router_kernel<<<NTOK / 4, 256, 0, stream>>>(x, rw, rb, tok_experts, tok_gates);
  scan_kernel<<<NEXP, 1024, 0, stream>>>(tok_experts, slot_token, token_rows);
  convert_x_kernel<<<NTOK * D_MODEL / (256 * 8), 256, 0, stream>>>(x, xbf);
  transpose_kernel<<<dim3(D_HIDDEN / 64, D_MODEL / 64, NEXP), 256, 0, stream>>>(
      w1, w1t, D_MODEL, D_HIDDEN);
  transpose_kernel<<<dim3(D_MODEL / 64, D_HIDDEN / 64, NEXP), 256, 0, stream>>>(
      w2, w2t, D_HIDDEN, D_MODEL);
  gemm_8phase<1><<<640, 512, 0, stream>>>(xbf, w1t, b1, slot_token, h,
                                          nullptr, nullptr, nullptr);
  gemm_8phase<2><<<640, 512, 0, stream>>>(h, w2t, b2, nullptr, part0, part1,
                                          part2, part3);
  combine_kernel<<<NTOK, 256, 0, stream>>>(token_rows, tok_gates, part0, part1,
                                           part2, part3, y);
}